// Round 17
// baseline (356.841 us; speedup 1.0000x reference)
//
#include <hip/hip_runtime.h>
#include <hip/hip_bf16.h>
#include <math.h>

#define N_NODES 100000
#define N_EDGES 1000000
#define DIM 64
#define AGPAD 72          // LDS row stride in shorts (144 B = 16-B aligned)

// Device dtypes (established empirically R1-R8): fp32 floats, int32 indices,
// fp32 output.
// R11: grid.sync() costs ~80-90 us on 8-XCD MI355X -- never use it.
// R12: bucket CSR slows all consumers; compact CSR + scan wins.
// R13/R14: cross-block publish/consume inside one dispatch kills containers.
// R16: deriving indices from assumed-uniform poison killed containers (first
// correctness call may see non-uniform ws) -- always memset what you index by.
typedef __hip_bfloat16 bf16;
typedef __attribute__((ext_vector_type(8))) short short8;
typedef __attribute__((ext_vector_type(4))) float floatx4;

__device__ __forceinline__ float b2f(bf16 v) { return __bfloat162float(v); }

__device__ __forceinline__ unsigned int packbf2(float a, float b) {
    bf16 x = __float2bfloat16(a), y = __float2bfloat16(b);
    unsigned short ux = *(unsigned short*)&x, uy = *(unsigned short*)&y;
    return (unsigned int)ux | ((unsigned int)uy << 16);
}

__device__ __forceinline__ short f2bs(float v) {
    bf16 x = __float2bfloat16(v);
    return *(short*)&x;
}

__device__ __forceinline__ float2 upk(unsigned int u) {
    unsigned short lo = (unsigned short)(u & 0xffff);
    unsigned short hi = (unsigned short)(u >> 16);
    bf16 a = *(bf16*)&lo, b = *(bf16*)&hi;
    return make_float2(b2f(a), b2f(b));
}

__device__ __forceinline__ int clampN(int v) {
    return v < 0 ? 0 : (v >= N_NODES ? N_NODES - 1 : v);
}

// ---------------------------------------------------------------------------
// Fused pre-pass (R10-proven), disjoint block ranges:
//   blocks [0,977)    : degree histogram + per-edge rank capture (pos)
//   blocks [977,7227) : x fp32 -> xb bf16 rows (1.6M float4s exactly)
//   block  7227       : wt[d][k] = bf16 [Wl0 | Wr0] row-concat
// degi zeroed by the preceding memsetAsync.
// ---------------------------------------------------------------------------
__global__ void hist_convert_kernel(const int* __restrict__ ei,
                                    int* __restrict__ degi,
                                    int* __restrict__ pos,
                                    const float4* __restrict__ x4,
                                    uint2* __restrict__ xb4,
                                    const float* __restrict__ Wl0,
                                    const float* __restrict__ Wr0,
                                    short* __restrict__ wt) {
    int b = blockIdx.x;
    if (b < 977) {
        int idx = b * 256 + threadIdx.x;
        if (idx < N_EDGES / 4) {
            int4 d4 = ((const int4*)(ei + N_EDGES))[idx];
            int4 p;
            p.x = atomicAdd(&degi[clampN(d4.x)], 1);
            p.y = atomicAdd(&degi[clampN(d4.y)], 1);
            p.z = atomicAdd(&degi[clampN(d4.z)], 1);
            p.w = atomicAdd(&degi[clampN(d4.w)], 1);
            ((int4*)pos)[idx] = p;
        }
    } else if (b < 7227) {
        int idx = (b - 977) * 256 + threadIdx.x;   // < 1,600,000 exactly
        float4 f = x4[idx];
        xb4[idx] = make_uint2(packbf2(f.x, f.y), packbf2(f.z, f.w));
    } else {
        for (int i = threadIdx.x; i < 8192; i += 256) {
            int d = i >> 7, k = i & 127;
            float v = (k < 64) ? Wl0[d * 64 + k] : Wr0[d * 64 + (k - 64)];
            wt[i] = f2bs(v);
        }
    }
}

// ---------------------------------------------------------------------------
// Single-workgroup scan (1 block x 1024 threads; ALL sync intra-block -- none
// of the R13 cross-block hazard class). Thread owns 98 contiguous elements:
// serial chunk sum -> 1024-wide LDS exclusive scan -> write exclusive
// rowstart. Replaces scan1+scan2 (one launch instead of two).
// ---------------------------------------------------------------------------
__global__ void scan_kernel(const int* __restrict__ degi,
                            int* __restrict__ rowstart) {
    __shared__ int sc[1024];
    const int tid = threadIdx.x;
    int start = tid * 98;
    int end = start + 98;
    if (start > N_NODES) start = N_NODES;
    if (end > N_NODES) end = N_NODES;
    int sum = 0;
    for (int k = start; k < end; ++k) sum += degi[k];
    sc[tid] = sum;
    __syncthreads();
    #pragma unroll
    for (int off = 1; off < 1024; off <<= 1) {
        int u = (tid >= off) ? sc[tid - off] : 0;
        __syncthreads();
        sc[tid] += u;
        __syncthreads();
    }
    int off0 = sc[tid] - sum;   // exclusive prefix of this chunk
    for (int k = start; k < end; ++k) {
        rowstart[k] = off0;
        off0 += degi[k];
    }
}

// fill: pure scatter, no atomics (pos carries each edge's rank from hist).
__global__ void fill_kernel(const int* __restrict__ ei,
                            const int* __restrict__ rowstart,
                            const int* __restrict__ pos,
                            int* __restrict__ csr) {
    int idx = blockIdx.x * blockDim.x + threadIdx.x;
    if (idx < N_EDGES / 4) {
        int4 s4 = ((const int4*)ei)[idx];
        int4 d4 = ((const int4*)(ei + N_EDGES))[idx];
        int4 p4 = ((const int4*)pos)[idx];
        int d;
        d = clampN(d4.x); csr[rowstart[d] + p4.x] = clampN(s4.x);
        d = clampN(d4.y); csr[rowstart[d] + p4.y] = clampN(s4.y);
        d = clampN(d4.z); csr[rowstart[d] + p4.z] = clampN(s4.z);
        d = clampN(d4.w); csr[rowstart[d] + p4.w] = clampN(s4.w);
    }
}

// ---------------------------------------------------------------------------
// Fused aggregate + MFMA GEMM + heads. Block = 256 threads = 16 nodes.
// Phase 1: 16-lane quarter-wave per node; lane owns 4 dims; 8 independent
//   edge-row gathers in flight; bf16 mean -> LDS As[16][AGPAD].
// Phase 2: wave w computes output dims d = w*16 + r via 4x
//   mfma_f32_16x16x32_bf16 over K=128 = [mean | x]; B = wt rows (L1-resident);
//   C/D: node = quad*4+reg, d = r (R9/R10-verified). Epilogue: relu + dual
//   head dots, 16-lane shfl reduce, LDS-atomic combine across waves.
// ---------------------------------------------------------------------------
__global__ __launch_bounds__(256) void agg_gemm_kernel(
        const uint2* __restrict__ xb2, const short* __restrict__ xb,
        const short* __restrict__ wt,
        const int* __restrict__ rowstart,
        const int* __restrict__ degi, const int* __restrict__ csr,
        const float* __restrict__ bl0, const float* __restrict__ Wl1,
        const float* __restrict__ Wr1,
        float* __restrict__ s, float* __restrict__ t) {
    __shared__ short As[16 * AGPAD];
    __shared__ float sRed[16], tRed[16];
    const int tid = threadIdx.x;
    const int nb = blockIdx.x * 16;          // 100000 = 6250*16, always full

    if (tid < 16) { sRed[tid] = 0.0f; tRed[tid] = 0.0f; }

    // ---- phase 1: aggregate (8-deep MLP) ----
    {
        int qn = tid >> 4;     // node-local 0..15
        int l  = tid & 15;     // lane in quarter: dims 4l..4l+3
        int n = nb + qn;
        int beg = rowstart[n];
        int cnt = degi[n];
        float4 A0 = make_float4(0.f, 0.f, 0.f, 0.f);
        float4 A1 = A0, A2 = A0, A3 = A0, A4 = A0, A5 = A0, A6 = A0, A7 = A0;
        int i = 0;
        for (; i + 8 <= cnt; i += 8) {
            int e0 = csr[beg + i],     e1 = csr[beg + i + 1];
            int e2 = csr[beg + i + 2], e3 = csr[beg + i + 3];
            int e4 = csr[beg + i + 4], e5 = csr[beg + i + 5];
            int e6 = csr[beg + i + 6], e7 = csr[beg + i + 7];
            uint2 u0 = xb2[(long)e0 * 16 + l];
            uint2 u1 = xb2[(long)e1 * 16 + l];
            uint2 u2 = xb2[(long)e2 * 16 + l];
            uint2 u3 = xb2[(long)e3 * 16 + l];
            uint2 u4 = xb2[(long)e4 * 16 + l];
            uint2 u5 = xb2[(long)e5 * 16 + l];
            uint2 u6 = xb2[(long)e6 * 16 + l];
            uint2 u7 = xb2[(long)e7 * 16 + l];
            float2 f;
            f = upk(u0.x); A0.x += f.x; A0.y += f.y; f = upk(u0.y); A0.z += f.x; A0.w += f.y;
            f = upk(u1.x); A1.x += f.x; A1.y += f.y; f = upk(u1.y); A1.z += f.x; A1.w += f.y;
            f = upk(u2.x); A2.x += f.x; A2.y += f.y; f = upk(u2.y); A2.z += f.x; A2.w += f.y;
            f = upk(u3.x); A3.x += f.x; A3.y += f.y; f = upk(u3.y); A3.z += f.x; A3.w += f.y;
            f = upk(u4.x); A4.x += f.x; A4.y += f.y; f = upk(u4.y); A4.z += f.x; A4.w += f.y;
            f = upk(u5.x); A5.x += f.x; A5.y += f.y; f = upk(u5.y); A5.z += f.x; A5.w += f.y;
            f = upk(u6.x); A6.x += f.x; A6.y += f.y; f = upk(u6.y); A6.z += f.x; A6.w += f.y;
            f = upk(u7.x); A7.x += f.x; A7.y += f.y; f = upk(u7.y); A7.z += f.x; A7.w += f.y;
        }
        if (i + 4 <= cnt) {
            int e0 = csr[beg + i],     e1 = csr[beg + i + 1];
            int e2 = csr[beg + i + 2], e3 = csr[beg + i + 3];
            uint2 u0 = xb2[(long)e0 * 16 + l];
            uint2 u1 = xb2[(long)e1 * 16 + l];
            uint2 u2 = xb2[(long)e2 * 16 + l];
            uint2 u3 = xb2[(long)e3 * 16 + l];
            float2 f;
            f = upk(u0.x); A0.x += f.x; A0.y += f.y; f = upk(u0.y); A0.z += f.x; A0.w += f.y;
            f = upk(u1.x); A1.x += f.x; A1.y += f.y; f = upk(u1.y); A1.z += f.x; A1.w += f.y;
            f = upk(u2.x); A2.x += f.x; A2.y += f.y; f = upk(u2.y); A2.z += f.x; A2.w += f.y;
            f = upk(u3.x); A3.x += f.x; A3.y += f.y; f = upk(u3.y); A3.z += f.x; A3.w += f.y;
            i += 4;
        }
        if (i < cnt) {
            uint2 u = xb2[(long)csr[beg + i] * 16 + l];
            float2 f = upk(u.x); A4.x += f.x; A4.y += f.y;
            f = upk(u.y); A4.z += f.x; A4.w += f.y;
        }
        if (i + 1 < cnt) {
            uint2 u = xb2[(long)csr[beg + i + 1] * 16 + l];
            float2 f = upk(u.x); A5.x += f.x; A5.y += f.y;
            f = upk(u.y); A5.z += f.x; A5.w += f.y;
        }
        if (i + 2 < cnt) {
            uint2 u = xb2[(long)csr[beg + i + 2] * 16 + l];
            float2 f = upk(u.x); A6.x += f.x; A6.y += f.y;
            f = upk(u.y); A6.z += f.x; A6.w += f.y;
        }
        float inv = 1.0f / fmaxf((float)cnt, 1.0f);
        float ax = (((A0.x + A1.x) + (A2.x + A3.x)) + ((A4.x + A5.x) + (A6.x + A7.x))) * inv;
        float ay = (((A0.y + A1.y) + (A2.y + A3.y)) + ((A4.y + A5.y) + (A6.y + A7.y))) * inv;
        float az = (((A0.z + A1.z) + (A2.z + A3.z)) + ((A4.z + A5.z) + (A6.z + A7.z))) * inv;
        float aw = (((A0.w + A1.w) + (A2.w + A3.w)) + ((A4.w + A5.w) + (A6.w + A7.w))) * inv;
        *(uint2*)&As[qn * AGPAD + 4 * l] =
            make_uint2(packbf2(ax, ay), packbf2(az, aw));
    }
    __syncthreads();

    // ---- phase 2: MFMA + heads ----
    const int lane = tid & 63;
    const int w = tid >> 6;
    const int r = lane & 15;
    const int quad = lane >> 4;

    short8 a0 = *(const short8*)&As[r * AGPAD + quad * 8];        // k  0..31
    short8 a1 = *(const short8*)&As[r * AGPAD + 32 + quad * 8];   // k 32..63
    const long xrow = (long)(nb + r) * 64 + quad * 8;
    short8 a2 = *(const short8*)(xb + xrow);                      // k 64..95
    short8 a3 = *(const short8*)(xb + xrow + 32);                 // k 96..127

    const int d = w * 16 + r;
    const short* brow = wt + (long)d * 128 + quad * 8;
    short8 b0 = *(const short8*)(brow);
    short8 b1 = *(const short8*)(brow + 32);
    short8 b2 = *(const short8*)(brow + 64);
    short8 b3 = *(const short8*)(brow + 96);

    float bb = bl0[d];
    floatx4 acc = {bb, bb, bb, bb};
    acc = __builtin_amdgcn_mfma_f32_16x16x32_bf16(a0, b0, acc, 0, 0, 0);
    acc = __builtin_amdgcn_mfma_f32_16x16x32_bf16(a1, b1, acc, 0, 0, 0);
    acc = __builtin_amdgcn_mfma_f32_16x16x32_bf16(a2, b2, acc, 0, 0, 0);
    acc = __builtin_amdgcn_mfma_f32_16x16x32_bf16(a3, b3, acc, 0, 0, 0);

    float w1 = Wl1[d], w2 = Wr1[d];
    float hs[4], ht[4];
    #pragma unroll
    for (int g = 0; g < 4; ++g) {
        float h = fmaxf(acc[g], 0.0f);
        hs[g] = h * w1;
        ht[g] = h * w2;
    }
    #pragma unroll
    for (int g = 0; g < 4; ++g) {
        #pragma unroll
        for (int off = 1; off < 16; off <<= 1) {
            hs[g] += __shfl_xor(hs[g], off, 64);
            ht[g] += __shfl_xor(ht[g], off, 64);
        }
    }
    if (r == 0) {
        #pragma unroll
        for (int g = 0; g < 4; ++g) {
            atomicAdd(&sRed[quad * 4 + g], hs[g]);
            atomicAdd(&tRed[quad * 4 + g], ht[g]);
        }
    }
    __syncthreads();
    if (tid < 16) {
        s[nb + tid] = sRed[tid];
        t[nb + tid] = tRed[tid];
    }
}

// ---------------------------------------------------------------------------
// Final: CSR-gather of s (8-wide ILP), mean, + bl1 + t, sigmoid, fp32 out.
// ---------------------------------------------------------------------------
__global__ void final_kernel(const float* __restrict__ s,
                             const float* __restrict__ t,
                             const int* __restrict__ rowstart,
                             const int* __restrict__ degi,
                             const int* __restrict__ csr,
                             const float* __restrict__ bl1,
                             float* __restrict__ out) {
    int n = blockIdx.x * 256 + threadIdx.x;
    if (n >= N_NODES) return;
    int beg = rowstart[n];
    int cnt = degi[n];
    float a0 = 0.f, a1 = 0.f, a2 = 0.f, a3 = 0.f;
    float a4 = 0.f, a5 = 0.f, a6 = 0.f, a7 = 0.f;
    int i = 0;
    for (; i + 8 <= cnt; i += 8) {
        int e0 = csr[beg + i],     e1 = csr[beg + i + 1];
        int e2 = csr[beg + i + 2], e3 = csr[beg + i + 3];
        int e4 = csr[beg + i + 4], e5 = csr[beg + i + 5];
        int e6 = csr[beg + i + 6], e7 = csr[beg + i + 7];
        a0 += s[e0]; a1 += s[e1]; a2 += s[e2]; a3 += s[e3];
        a4 += s[e4]; a5 += s[e5]; a6 += s[e6]; a7 += s[e7];
    }
    if (i + 4 <= cnt) {
        int e0 = csr[beg + i],     e1 = csr[beg + i + 1];
        int e2 = csr[beg + i + 2], e3 = csr[beg + i + 3];
        a0 += s[e0]; a1 += s[e1]; a2 += s[e2]; a3 += s[e3];
        i += 4;
    }
    if (i < cnt)     a4 += s[csr[beg + i]];
    if (i + 1 < cnt) a5 += s[csr[beg + i + 1]];
    if (i + 2 < cnt) a6 += s[csr[beg + i + 2]];
    float acc = ((a0 + a1) + (a2 + a3)) + ((a4 + a5) + (a6 + a7));
    float v = acc / fmaxf((float)cnt, 1.0f) + bl1[0] + t[n];
    float sg = 1.0f / (1.0f + expf(-v));
    out[n] = v;
    out[N_NODES + n] = sg;
}

extern "C" void kernel_launch(void* const* d_in, const int* in_sizes, int n_in,
                              void* d_out, int out_size, void* d_ws, size_t ws_size,
                              hipStream_t stream) {
    const float* x   = (const float*)d_in[0];
    const int*   ei  = (const int*)d_in[1];   // int32, [2,E] flat: src row, dst row
    const float* Wl0 = (const float*)d_in[2];
    const float* bl0 = (const float*)d_in[3];
    const float* Wr0 = (const float*)d_in[4];
    const float* Wl1 = (const float*)d_in[5];
    const float* bl1 = (const float*)d_in[6];
    const float* Wr1 = (const float*)d_in[7];
    float* out = (float*)d_out;

    // Workspace layout (~22.4 MB, 16-B aligned offsets):
    //   degi     @0            (400,000)   zeroed by memsetAsync
    //   rowstart @400,000      (400,000)
    //   s        @800,000      (400,000)
    //   t        @1,200,000    (400,000)
    //   csr      @1,600,000    (4,000,000)
    //   pos      @5,600,000    (4,000,000)
    //   xb       @9,600,000    (12,800,000)  bf16 x rows
    //   wt       @22,400,000   (16,384)      bf16 [Wl0|Wr0] rows
    char* ws = (char*)d_ws;
    int*   degi     = (int*)(ws);
    int*   rowstart = (int*)(ws + 400000);
    float* s        = (float*)(ws + 800000);
    float* t        = (float*)(ws + 1200000);
    int*   csr      = (int*)(ws + 1600000);
    int*   pos      = (int*)(ws + 5600000);
    char*  xb       = (ws + 9600000);
    short* wt       = (short*)(ws + 22400000);

    (void)hipMemsetAsync(degi, 0, 400000, stream);

    hist_convert_kernel<<<7228, 256, 0, stream>>>(ei, degi, pos,
                                                  (const float4*)x, (uint2*)xb,
                                                  Wl0, Wr0, wt);
    scan_kernel<<<1, 1024, 0, stream>>>(degi, rowstart);
    fill_kernel<<<977, 256, 0, stream>>>(ei, rowstart, pos, csr);
    agg_gemm_kernel<<<6250, 256, 0, stream>>>((const uint2*)xb, (const short*)xb,
                                              wt, rowstart, degi, csr,
                                              bl0, Wl1, Wr1, s, t);
    final_kernel<<<391, 256, 0, stream>>>(s, t, rowstart, degi, csr, bl1, out);
}

// Round 18
// 202.097 us; speedup vs baseline: 1.7657x; 1.7657x over previous
//
#include <hip/hip_runtime.h>
#include <hip/hip_bf16.h>
#include <math.h>

#define N_NODES 100000
#define N_EDGES 1000000
#define DIM 64
#define SCAN_BLOCKS 391   // ceil(N_NODES/256)
#define AGPAD 72          // LDS row stride in shorts (144 B = 16-B aligned)

// Device dtypes (established empirically R1-R8): fp32 floats, int32 indices,
// fp32 output.
// R11: grid.sync() costs ~80-90 us on 8-XCD MI355X -- never use it.
// R12: bucket CSR slows all consumers; compact CSR + scan wins.
// R13/R14: cross-block publish/consume inside one dispatch kills containers.
// R16: never derive indices from assumed-uniform poison; memset what you index.
// R17: 1-block scan over 100k elems = 160 us latency catastrophe; parallel
// tile scan (scan1+scan2) does it in ~6 us. R15: 8-deep unrolls ~9 us worse
// than 4-deep at deg~10 -- reverted.
typedef __hip_bfloat16 bf16;
typedef __attribute__((ext_vector_type(8))) short short8;
typedef __attribute__((ext_vector_type(4))) float floatx4;

__device__ __forceinline__ float b2f(bf16 v) { return __bfloat162float(v); }

__device__ __forceinline__ unsigned int packbf2(float a, float b) {
    bf16 x = __float2bfloat16(a), y = __float2bfloat16(b);
    unsigned short ux = *(unsigned short*)&x, uy = *(unsigned short*)&y;
    return (unsigned int)ux | ((unsigned int)uy << 16);
}

__device__ __forceinline__ short f2bs(float v) {
    bf16 x = __float2bfloat16(v);
    return *(short*)&x;
}

__device__ __forceinline__ float2 upk(unsigned int u) {
    unsigned short lo = (unsigned short)(u & 0xffff);
    unsigned short hi = (unsigned short)(u >> 16);
    bf16 a = *(bf16*)&lo, b = *(bf16*)&hi;
    return make_float2(b2f(a), b2f(b));
}

__device__ __forceinline__ int clampN(int v) {
    return v < 0 ? 0 : (v >= N_NODES ? N_NODES - 1 : v);
}

// ---------------------------------------------------------------------------
// Fused pre-pass, disjoint block ranges:
//   blocks [0,3907)     : degree histogram + rank capture, 1 edge/thread
//                         (R18: was 4 chained atomics/thread; 1M independent
//                         atomic chains instead of 250k x 4-serial)
//   blocks [3907,10157) : x fp32 -> xb bf16 rows (6250*256 = 1.6M float4s)
//   block  10157        : wt[d][k] = bf16 [Wl0 | Wr0] row-concat
// degi zeroed by the preceding memsetAsync.
// ---------------------------------------------------------------------------
__global__ void hist_convert_kernel(const int* __restrict__ ei,
                                    int* __restrict__ degi,
                                    int* __restrict__ pos,
                                    const float4* __restrict__ x4,
                                    uint2* __restrict__ xb4,
                                    const float* __restrict__ Wl0,
                                    const float* __restrict__ Wr0,
                                    short* __restrict__ wt) {
    int b = blockIdx.x;
    if (b < 3907) {
        int e = b * 256 + threadIdx.x;
        if (e < N_EDGES) {
            int dst = clampN(ei[N_EDGES + e]);
            pos[e] = atomicAdd(&degi[dst], 1);
        }
    } else if (b < 10157) {
        int idx = (b - 3907) * 256 + threadIdx.x;   // < 1,600,000 exactly
        float4 f = x4[idx];
        xb4[idx] = make_uint2(packbf2(f.x, f.y), packbf2(f.z, f.w));
    } else {
        for (int i = threadIdx.x; i < 8192; i += 256) {
            int d = i >> 7, k = i & 127;
            float v = (k < 64) ? Wl0[d * 64 + k] : Wr0[d * 64 + (k - 64)];
            wt[i] = f2bs(v);
        }
    }
}

// ---------------------------------------------------------------------------
// Two-kernel scan (R10-proven; ~6 us total).
// ---------------------------------------------------------------------------
__global__ void scan1_kernel(const int* __restrict__ degi,
                             int* __restrict__ rowstart, int* __restrict__ bsum) {
    __shared__ int sc[256];
    int t = threadIdx.x;
    int i = blockIdx.x * 256 + t;
    int v = (i < N_NODES) ? degi[i] : 0;
    sc[t] = v;
    __syncthreads();
    #pragma unroll
    for (int off = 1; off < 256; off <<= 1) {
        int u = (t >= off) ? sc[t - off] : 0;
        __syncthreads();
        sc[t] += u;
        __syncthreads();
    }
    if (i < N_NODES) rowstart[i] = sc[t] - v;   // exclusive within block
    if (t == 255) bsum[blockIdx.x] = sc[t];
}

__global__ void scan2_kernel(int* __restrict__ bsum) {
    __shared__ int sc[512];
    int t = threadIdx.x;
    int v = (t < SCAN_BLOCKS) ? bsum[t] : 0;
    sc[t] = v;
    __syncthreads();
    #pragma unroll
    for (int off = 1; off < 512; off <<= 1) {
        int u = (t >= off) ? sc[t - off] : 0;
        __syncthreads();
        sc[t] += u;
        __syncthreads();
    }
    if (t < SCAN_BLOCKS) bsum[t] = sc[t] - v;   // exclusive
}

// fill: pure scatter, no atomics (pos carries each edge's rank from hist).
__global__ void fill_kernel(const int* __restrict__ ei,
                            const int* __restrict__ rowstart,
                            const int* __restrict__ bsum,
                            const int* __restrict__ pos,
                            int* __restrict__ csr) {
    int idx = blockIdx.x * blockDim.x + threadIdx.x;
    if (idx < N_EDGES / 4) {
        int4 s4 = ((const int4*)ei)[idx];
        int4 d4 = ((const int4*)(ei + N_EDGES))[idx];
        int4 p4 = ((const int4*)pos)[idx];
        int d;
        d = clampN(d4.x); csr[rowstart[d] + bsum[d >> 8] + p4.x] = clampN(s4.x);
        d = clampN(d4.y); csr[rowstart[d] + bsum[d >> 8] + p4.y] = clampN(s4.y);
        d = clampN(d4.z); csr[rowstart[d] + bsum[d >> 8] + p4.z] = clampN(s4.z);
        d = clampN(d4.w); csr[rowstart[d] + bsum[d >> 8] + p4.w] = clampN(s4.w);
    }
}

// ---------------------------------------------------------------------------
// Fused aggregate + MFMA GEMM + heads (R10-proven). Block = 256 = 16 nodes.
// Phase 1: 16-lane quarter-wave per node; lane owns 4 dims (uint2 = 4 bf16),
//   4 independent edge-gather chains; bf16 mean -> LDS As[16][AGPAD].
// Phase 2: wave w computes output dims d = w*16 + r via 4x
//   mfma_f32_16x16x32_bf16 over K=128 = [mean | x]; B = wt rows (L1-resident);
//   C/D: node = quad*4+reg, d = r (R9/R10-verified). Epilogue: relu + dual
//   head dots, 16-lane shfl reduce, LDS-atomic combine across waves.
// ---------------------------------------------------------------------------
__global__ __launch_bounds__(256) void agg_gemm_kernel(
        const uint2* __restrict__ xb2, const short* __restrict__ xb,
        const short* __restrict__ wt,
        const int* __restrict__ rowstart, const int* __restrict__ bsum,
        const int* __restrict__ degi, const int* __restrict__ csr,
        const float* __restrict__ bl0, const float* __restrict__ Wl1,
        const float* __restrict__ Wr1,
        float* __restrict__ s, float* __restrict__ t) {
    __shared__ short As[16 * AGPAD];
    __shared__ float sRed[16], tRed[16];
    const int tid = threadIdx.x;
    const int nb = blockIdx.x * 16;          // 100000 = 6250*16, always full

    if (tid < 16) { sRed[tid] = 0.0f; tRed[tid] = 0.0f; }

    // ---- phase 1: aggregate ----
    {
        int qn = tid >> 4;     // node-local 0..15
        int l  = tid & 15;     // lane in quarter: dims 4l..4l+3
        int n = nb + qn;
        int beg = rowstart[n] + bsum[n >> 8];
        int cnt = degi[n];
        float4 A0 = make_float4(0.f, 0.f, 0.f, 0.f);
        float4 A1 = A0, A2 = A0, A3 = A0;
        int i = 0;
        for (; i + 4 <= cnt; i += 4) {
            int e0 = csr[beg + i],     e1 = csr[beg + i + 1];
            int e2 = csr[beg + i + 2], e3 = csr[beg + i + 3];
            uint2 u0 = xb2[(long)e0 * 16 + l];
            uint2 u1 = xb2[(long)e1 * 16 + l];
            uint2 u2 = xb2[(long)e2 * 16 + l];
            uint2 u3 = xb2[(long)e3 * 16 + l];
            float2 f;
            f = upk(u0.x); A0.x += f.x; A0.y += f.y; f = upk(u0.y); A0.z += f.x; A0.w += f.y;
            f = upk(u1.x); A1.x += f.x; A1.y += f.y; f = upk(u1.y); A1.z += f.x; A1.w += f.y;
            f = upk(u2.x); A2.x += f.x; A2.y += f.y; f = upk(u2.y); A2.z += f.x; A2.w += f.y;
            f = upk(u3.x); A3.x += f.x; A3.y += f.y; f = upk(u3.y); A3.z += f.x; A3.w += f.y;
        }
        if (i < cnt) {
            uint2 u = xb2[(long)csr[beg + i] * 16 + l];
            float2 f = upk(u.x); A0.x += f.x; A0.y += f.y;
            f = upk(u.y); A0.z += f.x; A0.w += f.y;
        }
        if (i + 1 < cnt) {
            uint2 u = xb2[(long)csr[beg + i + 1] * 16 + l];
            float2 f = upk(u.x); A1.x += f.x; A1.y += f.y;
            f = upk(u.y); A1.z += f.x; A1.w += f.y;
        }
        if (i + 2 < cnt) {
            uint2 u = xb2[(long)csr[beg + i + 2] * 16 + l];
            float2 f = upk(u.x); A2.x += f.x; A2.y += f.y;
            f = upk(u.y); A2.z += f.x; A2.w += f.y;
        }
        float inv = 1.0f / fmaxf((float)cnt, 1.0f);
        float ax = (A0.x + A1.x + A2.x + A3.x) * inv;
        float ay = (A0.y + A1.y + A2.y + A3.y) * inv;
        float az = (A0.z + A1.z + A2.z + A3.z) * inv;
        float aw = (A0.w + A1.w + A2.w + A3.w) * inv;
        *(uint2*)&As[qn * AGPAD + 4 * l] =
            make_uint2(packbf2(ax, ay), packbf2(az, aw));
    }
    __syncthreads();

    // ---- phase 2: MFMA + heads ----
    const int lane = tid & 63;
    const int w = tid >> 6;
    const int r = lane & 15;
    const int quad = lane >> 4;

    short8 a0 = *(const short8*)&As[r * AGPAD + quad * 8];        // k  0..31
    short8 a1 = *(const short8*)&As[r * AGPAD + 32 + quad * 8];   // k 32..63
    const long xrow = (long)(nb + r) * 64 + quad * 8;
    short8 a2 = *(const short8*)(xb + xrow);                      // k 64..95
    short8 a3 = *(const short8*)(xb + xrow + 32);                 // k 96..127

    const int d = w * 16 + r;
    const short* brow = wt + (long)d * 128 + quad * 8;
    short8 b0 = *(const short8*)(brow);
    short8 b1 = *(const short8*)(brow + 32);
    short8 b2 = *(const short8*)(brow + 64);
    short8 b3 = *(const short8*)(brow + 96);

    float bb = bl0[d];
    floatx4 acc = {bb, bb, bb, bb};
    acc = __builtin_amdgcn_mfma_f32_16x16x32_bf16(a0, b0, acc, 0, 0, 0);
    acc = __builtin_amdgcn_mfma_f32_16x16x32_bf16(a1, b1, acc, 0, 0, 0);
    acc = __builtin_amdgcn_mfma_f32_16x16x32_bf16(a2, b2, acc, 0, 0, 0);
    acc = __builtin_amdgcn_mfma_f32_16x16x32_bf16(a3, b3, acc, 0, 0, 0);

    float w1 = Wl1[d], w2 = Wr1[d];
    float hs[4], ht[4];
    #pragma unroll
    for (int g = 0; g < 4; ++g) {
        float h = fmaxf(acc[g], 0.0f);
        hs[g] = h * w1;
        ht[g] = h * w2;
    }
    #pragma unroll
    for (int g = 0; g < 4; ++g) {
        #pragma unroll
        for (int off = 1; off < 16; off <<= 1) {
            hs[g] += __shfl_xor(hs[g], off, 64);
            ht[g] += __shfl_xor(ht[g], off, 64);
        }
    }
    if (r == 0) {
        #pragma unroll
        for (int g = 0; g < 4; ++g) {
            atomicAdd(&sRed[quad * 4 + g], hs[g]);
            atomicAdd(&tRed[quad * 4 + g], ht[g]);
        }
    }
    __syncthreads();
    if (tid < 16) {
        s[nb + tid] = sRed[tid];
        t[nb + tid] = tRed[tid];
    }
}

// ---------------------------------------------------------------------------
// Final: CSR-gather of s (4-wide ILP, R10-proven), + bl1 + t, sigmoid.
// ---------------------------------------------------------------------------
__global__ void final_kernel(const float* __restrict__ s,
                             const float* __restrict__ t,
                             const int* __restrict__ rowstart,
                             const int* __restrict__ bsum,
                             const int* __restrict__ degi,
                             const int* __restrict__ csr,
                             const float* __restrict__ bl1,
                             float* __restrict__ out) {
    int n = blockIdx.x * 256 + threadIdx.x;
    if (n >= N_NODES) return;
    int beg = rowstart[n] + bsum[n >> 8];
    int cnt = degi[n];
    float acc = 0.0f;
    int i = 0;
    for (; i + 4 <= cnt; i += 4) {
        int e0 = csr[beg + i], e1 = csr[beg + i + 1];
        int e2 = csr[beg + i + 2], e3 = csr[beg + i + 3];
        acc += s[e0] + s[e1] + s[e2] + s[e3];
    }
    for (; i < cnt; ++i) acc += s[csr[beg + i]];
    float v = acc / fmaxf((float)cnt, 1.0f) + bl1[0] + t[n];
    float sg = 1.0f / (1.0f + expf(-v));
    out[n] = v;
    out[N_NODES + n] = sg;
}

extern "C" void kernel_launch(void* const* d_in, const int* in_sizes, int n_in,
                              void* d_out, int out_size, void* d_ws, size_t ws_size,
                              hipStream_t stream) {
    const float* x   = (const float*)d_in[0];
    const int*   ei  = (const int*)d_in[1];   // int32, [2,E] flat: src row, dst row
    const float* Wl0 = (const float*)d_in[2];
    const float* bl0 = (const float*)d_in[3];
    const float* Wr0 = (const float*)d_in[4];
    const float* Wl1 = (const float*)d_in[5];
    const float* bl1 = (const float*)d_in[6];
    const float* Wr1 = (const float*)d_in[7];
    float* out = (float*)d_out;

    // Workspace layout (~22.4 MB, 16-B aligned offsets):
    //   degi     @0            (400,000)   zeroed by memsetAsync
    //   rowstart @400,000      (400,000)
    //   bsum     @800,000      (4,096)
    //   s        @804,096      (400,000)
    //   t        @1,204,096    (400,000)
    //   csr      @1,604,096    (4,000,000)
    //   pos      @5,604,096    (4,000,000)
    //   xb       @9,604,096    (12,800,000)  bf16 x rows
    //   wt       @22,404,096   (16,384)      bf16 [Wl0|Wr0] rows
    char* ws = (char*)d_ws;
    int*   degi     = (int*)(ws);
    int*   rowstart = (int*)(ws + 400000);
    int*   bsum     = (int*)(ws + 800000);
    float* s        = (float*)(ws + 804096);
    float* t        = (float*)(ws + 1204096);
    int*   csr      = (int*)(ws + 1604096);
    int*   pos      = (int*)(ws + 5604096);
    char*  xb       = (ws + 9604096);
    short* wt       = (short*)(ws + 22404096);

    (void)hipMemsetAsync(degi, 0, 400000, stream);

    hist_convert_kernel<<<10158, 256, 0, stream>>>(ei, degi, pos,
                                                   (const float4*)x, (uint2*)xb,
                                                   Wl0, Wr0, wt);
    scan1_kernel<<<SCAN_BLOCKS, 256, 0, stream>>>(degi, rowstart, bsum);
    scan2_kernel<<<1, 512, 0, stream>>>(bsum);
    fill_kernel<<<977, 256, 0, stream>>>(ei, rowstart, bsum, pos, csr);
    agg_gemm_kernel<<<6250, 256, 0, stream>>>((const uint2*)xb, (const short*)xb,
                                              wt, rowstart, bsum, degi, csr,
                                              bl0, Wl1, Wr1, s, t);
    final_kernel<<<SCAN_BLOCKS, 256, 0, stream>>>(s, t, rowstart, bsum, degi, csr,
                                                  bl1, out);
}